// Round 1
// baseline (1536.361 us; speedup 1.0000x reference)
//
#include <hip/hip_runtime.h>

namespace {
constexpr int kB = 32;       // batch
constexpr int kN = 32768;    // num_primary
constexpr int kQ = 8;        // dim_primary
constexpr int kD = 10;       // num_digit
constexpr int kV = 16;       // dim_digit
constexpr int kRows = kB * kD;    // 320 (b,d) rows
constexpr int kThreads = 320;     // 5 waves: lane layout t = d*32 + b
constexpr int kBlocks = 512;      // 2 blocks / CU
constexpr int kNT = kN / kBlocks; // 64 n per block
}

// One routing step. PHASE 0: c = 1/10 exactly (softmax of zero logits),
// no vprev needed. PHASE 1: logits = u_hat . vprev, softmax over d.
// s_out accumulated via fp32 atomics (zeroed by memset before launch).
template <int PHASE>
__launch_bounds__(kThreads)
__global__ void routing_pass(const float* __restrict__ u,     // [B,N,Q]
                             const float* __restrict__ W,     // [D,N,V,Q]
                             const float* __restrict__ vprev, // [B,D,V]
                             float* __restrict__ s_out) {     // [B,D,V]
  __shared__ float sm[kThreads];
  const int t = threadIdx.x;
  const int d = t >> 5;   // 0..9, same across each half-wave -> W broadcast
  const int b = t & 31;   // 0..31
  const int n0 = blockIdx.x * kNT;

  float vp[kV];
  if constexpr (PHASE != 0) {
    const float4* vpv = reinterpret_cast<const float4*>(vprev + (b * kD + d) * kV);
    #pragma unroll
    for (int i = 0; i < 4; ++i) {
      const float4 x = vpv[i];
      vp[i * 4 + 0] = x.x; vp[i * 4 + 1] = x.y;
      vp[i * 4 + 2] = x.z; vp[i * 4 + 3] = x.w;
    }
  }

  float acc[kV];
  #pragma unroll
  for (int v = 0; v < kV; ++v) acc[v] = 0.0f;

  // W[d][n][v][q]: 32 float4 per (d,n); advance 32 float4 per n.
  const float4* Wp = reinterpret_cast<const float4*>(W) +
                     ((long)d * kN + n0) * (kV * kQ / 4);
  const float4* up = reinterpret_cast<const float4*>(u) +
                     ((long)b * kN + n0) * (kQ / 4);

  for (int i = 0; i < kNT; ++i) {
    const float4 u0 = up[0];
    const float4 u1 = up[1];
    float uh[kV];
    #pragma unroll
    for (int v = 0; v < kV; ++v) {
      const float4 w0 = Wp[v * 2];
      const float4 w1 = Wp[v * 2 + 1];
      uh[v] = w0.x * u0.x + w0.y * u0.y + w0.z * u0.z + w0.w * u0.w +
              w1.x * u1.x + w1.y * u1.y + w1.z * u1.z + w1.w * u1.w;
    }

    float c;
    if constexpr (PHASE != 0) {
      float logit = 0.0f;
      #pragma unroll
      for (int v = 0; v < kV; ++v) logit = fmaf(uh[v], vp[v], logit);
      // softmax over d (10 values per b). |logit| <= ~15 so no max-sub needed.
      const float e = __expf(logit);
      sm[t] = e;
      __syncthreads();
      float den = 0.0f;
      #pragma unroll
      for (int j = 0; j < kD; ++j) den += sm[j * 32 + b];  // bank = b, conflict-free
      c = e * __builtin_amdgcn_rcpf(den);
      __syncthreads();
    } else {
      c = 1.0f;  // fold the exact 1/10 into the final scale
    }

    #pragma unroll
    for (int v = 0; v < kV; ++v) acc[v] = fmaf(c, uh[v], acc[v]);

    Wp += kV * kQ / 4;
    up += kQ / 4;
  }

  const float scale = (PHASE == 0) ? 0.1f : 1.0f;
  float* srow = s_out + (b * kD + d) * kV;
  #pragma unroll
  for (int v = 0; v < kV; ++v) atomicAdd(&srow[v], acc[v] * scale);
}

// squash per (b,d) row. MODE 0: vprev = squash(s)
//                       MODE 1: vprev += squash(s)   (builds v0+v1)
//                       MODE 2: out = squash(s)
template <int MODE>
__global__ void squash_kernel(const float* __restrict__ s,
                              float* __restrict__ vprev,
                              float* __restrict__ out) {
  const int t = threadIdx.x;
  if (t >= kRows) return;
  const float* sr = s + t * kV;
  float sv[kV];
  float n2 = 0.0f;
  #pragma unroll
  for (int v = 0; v < kV; ++v) {
    sv[v] = sr[v];
    n2 = fmaf(sv[v], sv[v], n2);
  }
  const float norm = sqrtf(n2);
  const float coef = n2 / ((n2 + 1.0f) * (norm + 1e-7f));
  float* dst = (MODE == 2) ? (out + t * kV) : (vprev + t * kV);
  #pragma unroll
  for (int v = 0; v < kV; ++v) {
    float val = coef * sv[v];
    if (MODE == 1) val += dst[v];
    dst[v] = val;
  }
}

extern "C" void kernel_launch(void* const* d_in, const int* in_sizes, int n_in,
                              void* d_out, int out_size, void* d_ws, size_t ws_size,
                              hipStream_t stream) {
  const float* u = reinterpret_cast<const float*>(d_in[0]);  // primary_caps [B,N,Q]
  const float* W = reinterpret_cast<const float*>(d_in[1]);  // W [D,N,V,Q]
  float* out = reinterpret_cast<float*>(d_out);              // v [B,D,V] fp32

  float* s = reinterpret_cast<float*>(d_ws);   // [B,D,V] accumulator
  float* vprev = s + kRows * kV;               // [B,D,V] running v / vsum
  const size_t sbytes = (size_t)kRows * kV * sizeof(float);

  // r = 0: c uniform -> s0 = 0.1 * sum_n u_hat ; v0 = squash(s0)
  hipMemsetAsync(s, 0, sbytes, stream);
  routing_pass<0><<<kBlocks, kThreads, 0, stream>>>(u, W, nullptr, s);
  squash_kernel<0><<<1, kThreads, 0, stream>>>(s, vprev, out);

  // r = 1: logits = u_hat . v0 ; v1 = squash(s1) ; vprev = v0 + v1
  hipMemsetAsync(s, 0, sbytes, stream);
  routing_pass<1><<<kBlocks, kThreads, 0, stream>>>(u, W, vprev, s);
  squash_kernel<1><<<1, kThreads, 0, stream>>>(s, vprev, out);

  // r = 2: logits = u_hat . (v0+v1) ; out = squash(s2)
  hipMemsetAsync(s, 0, sbytes, stream);
  routing_pass<1><<<kBlocks, kThreads, 0, stream>>>(u, W, vprev, s);
  squash_kernel<2><<<1, kThreads, 0, stream>>>(s, vprev, out);
}

// Round 2
// 1440.753 us; speedup vs baseline: 1.0664x; 1.0664x over previous
//
#include <hip/hip_runtime.h>
#include <stdint.h>

namespace {
constexpr int kB = 32;       // batch
constexpr int kN = 32768;    // num_primary
constexpr int kQ = 8;        // dim_primary
constexpr int kD = 10;       // num_digit
constexpr int kV = 16;       // dim_digit
constexpr int kRows = kB * kD;            // 320
constexpr int kNT = 4;                    // n per tile
constexpr int kTiles = kN / kNT;          // 8192
constexpr int kThreads = 512;             // 32 b * 16 lanes (10 active d)
constexpr int kGrid = 512;                // 2 blocks/CU, 16 tiles/block
// LDS layout per buffer: W rows padded +16B so the 10 d-rows hit different banks.
constexpr int kWRow = kNT * kV * kQ * 4;          // 2048 B of W per d
constexpr int kWStride = kWRow + 16;              // 2064 B (bank offset 4 per d)
constexpr int kWBytes = kD * kWStride;            // 20640 B
constexpr int kUBytes = kB * kNT * kQ * 4;        // 4096 B
constexpr int kBufBytes = kWBytes + kUBytes;      // 24736 B (16-aligned)
}

__device__ __forceinline__ void g2lds16(const void* g, void* l) {
  __builtin_amdgcn_global_load_lds(
      (const __attribute__((address_space(1))) unsigned int*)g,
      (__attribute__((address_space(3))) unsigned int*)l, 16, 0, 0);
}

// Stage one tile (4 n): 20 W segments of 1KB + 4 u segments of 1KB.
// 8 waves * 3 segs = 24 segs exactly. dst base is wave-uniform (HW adds lane*16);
// src is per-lane.
__device__ __forceinline__ void stage_tile(const float* __restrict__ u,
                                           const float* __restrict__ W,
                                           char* buf, int n0) {
  const int wv = threadIdx.x >> 6;
  const int ln = threadIdx.x & 63;
  #pragma unroll
  for (int k = 0; k < 3; ++k) {
    const int s = wv + 8 * k;  // 0..23, wave-uniform
    if (s < 20) {
      const int d = s >> 1, half = s & 1;
      const char* src = (const char*)W + ((size_t)d * kN + n0) * 512 +
                        (size_t)half * 1024 + (size_t)ln * 16;
      char* dst = buf + d * kWStride + half * 1024;
      g2lds16(src, dst);
    } else {
      const int s2 = s - 20;                    // 0..3
      const int b = s2 * 8 + (ln >> 3);         // 8 b per segment (128 B each)
      const char* src = (const char*)u + ((size_t)b * kN + n0) * 32 +
                        (size_t)(ln & 7) * 16;
      char* dst = buf + kWBytes + s2 * 1024;
      g2lds16(src, dst);
    }
  }
}

// PHASE 0: c = 1/10 exactly (folded into final scale). PHASE 1: softmax(u_hat.vprev).
template <int PHASE>
__launch_bounds__(kThreads, 4)
__global__ void routing_pass(const float* __restrict__ u,     // [B,N,Q]
                             const float* __restrict__ W,     // [D,N,V,Q]
                             const float* __restrict__ vprev, // [B,D,V]
                             float* __restrict__ s_out) {     // [B,D,V]
  __shared__ __align__(16) char smem[2 * kBufBytes];
  const int t = threadIdx.x;
  const int b = t >> 4;       // 0..31
  const int d = t & 15;       // 0..15, active if d < 10; softmax group = 16 lanes
  const bool act = (d < kD);
  const int dd = act ? d : 0; // idle lanes read d=0 rows (broadcast, harmless)

  float vp[kV];
  if constexpr (PHASE != 0) {
    const float4* vr = (const float4*)(vprev + (b * kD + dd) * kV);
    #pragma unroll
    for (int i = 0; i < 4; ++i) {
      const float4 x = vr[i];
      vp[4 * i + 0] = x.x; vp[4 * i + 1] = x.y;
      vp[4 * i + 2] = x.z; vp[4 * i + 3] = x.w;
    }
  }

  float acc[kV];
  #pragma unroll
  for (int v = 0; v < kV; ++v) acc[v] = 0.0f;

  int tile = blockIdx.x;
  int cur = 0;
  stage_tile(u, W, smem, tile * kNT);

  for (; tile < kTiles; tile += gridDim.x) {
    __syncthreads();  // drains vmcnt: cur buffer staged; prev reads done
    const int nxt = tile + gridDim.x;
    if (nxt < kTiles)
      stage_tile(u, W, smem + (cur ^ 1) * kBufBytes, nxt * kNT);  // async overlap

    const char* wbase = smem + cur * kBufBytes + dd * kWStride;
    const char* ubase = smem + cur * kBufBytes + kWBytes + b * (kNT * kQ * 4);
    #pragma unroll
    for (int n = 0; n < kNT; ++n) {
      const float4* wr = (const float4*)(wbase + n * 512);
      const float4* ur = (const float4*)(ubase + n * 32);
      const float4 u0 = ur[0], u1 = ur[1];
      float uh[kV];
      #pragma unroll
      for (int v = 0; v < kV; ++v) {
        const float4 w0 = wr[v * 2];
        const float4 w1 = wr[v * 2 + 1];
        float s0 = w0.x * u0.x;
        s0 = fmaf(w0.y, u0.y, s0); s0 = fmaf(w0.z, u0.z, s0);
        s0 = fmaf(w0.w, u0.w, s0); s0 = fmaf(w1.x, u1.x, s0);
        s0 = fmaf(w1.y, u1.y, s0); s0 = fmaf(w1.z, u1.z, s0);
        s0 = fmaf(w1.w, u1.w, s0);
        uh[v] = s0;
      }
      float c;
      if constexpr (PHASE != 0) {
        float lg = 0.0f;
        #pragma unroll
        for (int v = 0; v < kV; ++v) lg = fmaf(uh[v], vp[v], lg);
        const float e = act ? __expf(lg) : 0.0f;
        float den = e;  // reduce across the 16-lane d-group (idle lanes add 0)
        den += __shfl_xor(den, 1, 16);
        den += __shfl_xor(den, 2, 16);
        den += __shfl_xor(den, 4, 16);
        den += __shfl_xor(den, 8, 16);
        c = e * __builtin_amdgcn_rcpf(den);
      } else {
        c = 1.0f;
      }
      #pragma unroll
      for (int v = 0; v < kV; ++v) acc[v] = fmaf(c, uh[v], acc[v]);
    }
    cur ^= 1;
  }

  if (act) {
    const float scale = (PHASE == 0) ? 0.1f : 1.0f;
    float* srow = s_out + (b * kD + d) * kV;
    #pragma unroll
    for (int v = 0; v < kV; ++v) atomicAdd(&srow[v], acc[v] * scale);
  }
}

// squash per (b,d) row. MODE 0: vprev = squash(s)
//                       MODE 1: vprev += squash(s)   (builds v0+v1)
//                       MODE 2: out = squash(s)
template <int MODE>
__global__ void squash_kernel(const float* __restrict__ s,
                              float* __restrict__ vprev,
                              float* __restrict__ out) {
  const int t = threadIdx.x;
  if (t >= kRows) return;
  const float* sr = s + t * kV;
  float sv[kV];
  float n2 = 0.0f;
  #pragma unroll
  for (int v = 0; v < kV; ++v) {
    sv[v] = sr[v];
    n2 = fmaf(sv[v], sv[v], n2);
  }
  const float norm = sqrtf(n2);
  const float coef = n2 / ((n2 + 1.0f) * (norm + 1e-7f));
  float* dst = (MODE == 2) ? (out + t * kV) : (vprev + t * kV);
  #pragma unroll
  for (int v = 0; v < kV; ++v) {
    float val = coef * sv[v];
    if (MODE == 1) val += dst[v];
    dst[v] = val;
  }
}

extern "C" void kernel_launch(void* const* d_in, const int* in_sizes, int n_in,
                              void* d_out, int out_size, void* d_ws, size_t ws_size,
                              hipStream_t stream) {
  const float* u = reinterpret_cast<const float*>(d_in[0]);  // primary_caps [B,N,Q]
  const float* W = reinterpret_cast<const float*>(d_in[1]);  // W [D,N,V,Q]
  float* out = reinterpret_cast<float*>(d_out);              // v [B,D,V] fp32

  float* s = reinterpret_cast<float*>(d_ws);   // [B,D,V] accumulator
  float* vprev = s + kRows * kV;               // [B,D,V] running v / vsum
  const size_t sbytes = (size_t)kRows * kV * sizeof(float);

  // r = 0: c uniform -> s0 = 0.1 * sum_n u_hat ; v0 = squash(s0)
  hipMemsetAsync(s, 0, sbytes, stream);
  routing_pass<0><<<kGrid, kThreads, 0, stream>>>(u, W, nullptr, s);
  squash_kernel<0><<<1, kThreads, 0, stream>>>(s, vprev, out);

  // r = 1: logits = u_hat . v0 ; v1 = squash(s1) ; vprev = v0 + v1
  hipMemsetAsync(s, 0, sbytes, stream);
  routing_pass<1><<<kGrid, kThreads, 0, stream>>>(u, W, vprev, s);
  squash_kernel<1><<<1, kThreads, 0, stream>>>(s, vprev, out);

  // r = 2: logits = u_hat . (v0+v1) ; out = squash(s2)
  hipMemsetAsync(s, 0, sbytes, stream);
  routing_pass<1><<<kGrid, kThreads, 0, stream>>>(u, W, vprev, s);
  squash_kernel<2><<<1, kThreads, 0, stream>>>(s, vprev, out);
}

// Round 3
// 840.409 us; speedup vs baseline: 1.8281x; 1.7143x over previous
//
#include <hip/hip_runtime.h>

namespace {
constexpr int kB = 32;       // batch
constexpr int kN = 32768;    // num_primary
constexpr int kQ = 8;        // dim_primary
constexpr int kD = 10;       // num_digit
constexpr int kV = 16;       // dim_digit
constexpr int kRows = kB * kD;        // 320
constexpr int kNT = 4;                // n per tile
constexpr int kTiles = kN / kNT;      // 8192
constexpr int kThreads = 512;         // 16 blocal x (16 dslot x 2 vh)
constexpr int kParts = 256;           // n-partitions; grid = 2 bgroups * kParts
constexpr int kGrid = 2 * kParts;
// LDS per buffer: W rows padded +16B per d; W stored per n-chunk in [j][vh] order.
constexpr int kWRow = kNT * kV * kQ * 4;     // 2048 B of W per d
constexpr int kWStride = kWRow + 16;         // 2064 B
constexpr int kWBytes = kD * kWStride;       // 20640 B
constexpr int kUBytes = 16 * kNT * kQ * 4;   // 2048 B (16 blocal x 128 B)
constexpr int kBufBytes = kWBytes + kUBytes; // 22688 B (16-aligned)
}

__device__ __forceinline__ void g2lds16(const void* g, void* l) {
  __builtin_amdgcn_global_load_lds(
      (const __attribute__((address_space(1))) unsigned int*)g,
      (__attribute__((address_space(3))) unsigned int*)l, 16, 0, 0);
}

// Stage one tile (4 n) for 16 b: 20 W segments of 1KB + 2 u segments of 1KB.
// 8 waves x 3 rounds = 24 slots (22 used). LDS dst base is wave-uniform
// (HW adds lane*16); the per-lane GLOBAL address carries the [j][vh]
// permutation so LDS holds, per 512B n-chunk: byte = j*64 + vh*32 + h*16.
__device__ __forceinline__ void stage_tile(const float* __restrict__ u,
                                           const float* __restrict__ W,
                                           char* buf, int n0, int bg) {
  const int wv = threadIdx.x >> 6;
  const int ln = threadIdx.x & 63;
  #pragma unroll
  for (int k = 0; k < 3; ++k) {
    const int s = wv + 8 * k;  // wave-uniform segment id
    if (s < 20) {
      const int d = s >> 1, half = s & 1;
      const int nh = ln >> 5, r = ln & 31;
      const int j = r >> 2, vh = (r >> 1) & 1, h = r & 1;
      const char* src = (const char*)W +
          ((size_t)d * kN + n0 + half * 2 + nh) * 512 +
          (size_t)(vh * 256 + j * 32 + h * 16);
      char* dst = buf + d * kWStride + half * 1024;
      g2lds16(src, dst);
    } else if (s < 22) {
      const int s2 = s - 20;                 // 0..1
      const int b = s2 * 8 + (ln >> 3);      // blocal, 128 B per b
      const char* src = (const char*)u +
          ((size_t)(bg * 16 + b) * kN + n0) * 32 + (size_t)(ln & 7) * 16;
      char* dst = buf + kWBytes + s2 * 1024;
      g2lds16(src, dst);
    }
  }
}

// PHASE 0: c = 1/10 exactly (folded into final scale). PHASE 1: softmax(u_hat.vprev).
template <int PHASE>
__launch_bounds__(kThreads, 4)
__global__ void routing_pass(const float* __restrict__ u,     // [B,N,Q]
                             const float* __restrict__ W,     // [D,N,V,Q]
                             const float* __restrict__ vprev, // [B,D,V]
                             float* __restrict__ s_out) {     // [B,D,V]
  __shared__ __align__(16) char smem[2 * kBufBytes];
  const int t = threadIdx.x;
  const int blocal = t >> 5;        // 0..15
  const int dslot = (t >> 1) & 15;  // 0..15, active if <10
  const int vh = t & 1;             // v-half
  const bool act = (dslot < kD);
  const int dd = act ? dslot : 0;
  const int bg = blockIdx.x >> 8;            // 0..1
  const int part = blockIdx.x & (kParts - 1);
  const int bglob = bg * 16 + blocal;

  float vp[8];
  if constexpr (PHASE != 0) {
    const float4* vr =
        (const float4*)(vprev + (bglob * kD + dd) * kV + vh * 8);
    const float4 x0 = vr[0], x1 = vr[1];
    vp[0] = x0.x; vp[1] = x0.y; vp[2] = x0.z; vp[3] = x0.w;
    vp[4] = x1.x; vp[5] = x1.y; vp[6] = x1.z; vp[7] = x1.w;
  }

  float acc[8];
  #pragma unroll
  for (int j = 0; j < 8; ++j) acc[j] = 0.0f;

  int tile = part;
  int cur = 0;
  stage_tile(u, W, smem, tile * kNT, bg);

  for (; tile < kTiles; tile += kParts) {
    __syncthreads();  // all waves: own staged loads drained, prev reads done
    const int nxt = tile + kParts;
    if (nxt < kTiles)
      stage_tile(u, W, smem + (cur ^ 1) * kBufBytes, nxt * kNT, bg);

    const char* wb = smem + cur * kBufBytes + dd * kWStride + vh * 32;
    const char* ub = smem + cur * kBufBytes + kWBytes + blocal * 128;
    #pragma unroll
    for (int n = 0; n < kNT; ++n) {
      const float4* ur = (const float4*)(ub + n * 32);
      const float4 u0 = ur[0], u1 = ur[1];
      float uh[8];
      #pragma unroll
      for (int j = 0; j < 8; ++j) {
        const float4* wr = (const float4*)(wb + n * 512 + j * 64);
        const float4 w0 = wr[0], w1 = wr[1];
        float s0 = w0.x * u0.x;
        s0 = fmaf(w0.y, u0.y, s0); s0 = fmaf(w0.z, u0.z, s0);
        s0 = fmaf(w0.w, u0.w, s0); s0 = fmaf(w1.x, u1.x, s0);
        s0 = fmaf(w1.y, u1.y, s0); s0 = fmaf(w1.z, u1.z, s0);
        s0 = fmaf(w1.w, u1.w, s0);
        uh[j] = s0;
      }
      float c;
      if constexpr (PHASE != 0) {
        float lg = 0.0f;
        #pragma unroll
        for (int j = 0; j < 8; ++j) lg = fmaf(uh[j], vp[j], lg);
        lg += __shfl_xor(lg, 1);  // sum the two v-halves
        const float e = act ? __expf(lg) : 0.0f;
        float den = e;            // softmax denom over the 16 d-slots
        den += __shfl_xor(den, 2);
        den += __shfl_xor(den, 4);
        den += __shfl_xor(den, 8);
        den += __shfl_xor(den, 16);
        c = e * __builtin_amdgcn_rcpf(den);
      } else {
        c = 1.0f;  // exact 1/10 folded into final scale
      }
      #pragma unroll
      for (int j = 0; j < 8; ++j) acc[j] = fmaf(c, uh[j], acc[j]);
    }
    cur ^= 1;
  }

  if (act) {
    const float scale = (PHASE == 0) ? 0.1f : 1.0f;
    float* srow = s_out + (bglob * kD + dslot) * kV + vh * 8;
    #pragma unroll
    for (int j = 0; j < 8; ++j) atomicAdd(&srow[j], acc[j] * scale);
  }
}

// squash per (b,d) row. MODE 0: vprev = squash(s); s = 0
//                       MODE 1: vprev += squash(s); s = 0
//                       MODE 2: out = squash(s)
template <int MODE>
__global__ void squash_kernel(float* __restrict__ s,
                              float* __restrict__ vprev,
                              float* __restrict__ out) {
  const int t = threadIdx.x;
  if (t >= kRows) return;
  float* sr = s + t * kV;
  float sv[kV];
  float n2 = 0.0f;
  #pragma unroll
  for (int v = 0; v < kV; ++v) {
    sv[v] = sr[v];
    n2 = fmaf(sv[v], sv[v], n2);
  }
  if (MODE != 2) {
    #pragma unroll
    for (int v = 0; v < kV; ++v) sr[v] = 0.0f;  // ready for next pass
  }
  const float norm = sqrtf(n2);
  const float coef = n2 / ((n2 + 1.0f) * (norm + 1e-7f));
  float* dst = (MODE == 2) ? (out + t * kV) : (vprev + t * kV);
  #pragma unroll
  for (int v = 0; v < kV; ++v) {
    float val = coef * sv[v];
    if (MODE == 1) val += dst[v];
    dst[v] = val;
  }
}

extern "C" void kernel_launch(void* const* d_in, const int* in_sizes, int n_in,
                              void* d_out, int out_size, void* d_ws, size_t ws_size,
                              hipStream_t stream) {
  const float* u = reinterpret_cast<const float*>(d_in[0]);  // primary_caps [B,N,Q]
  const float* W = reinterpret_cast<const float*>(d_in[1]);  // W [D,N,V,Q]
  float* out = reinterpret_cast<float*>(d_out);              // v [B,D,V] fp32

  float* s = reinterpret_cast<float*>(d_ws);   // [B,D,V] accumulator
  float* vprev = s + kRows * kV;               // [B,D,V] running v / vsum
  const size_t sbytes = (size_t)kRows * kV * sizeof(float);

  // r = 0: c uniform -> s0 = 0.1 * sum_n u_hat ; v0 = squash(s0)
  hipMemsetAsync(s, 0, sbytes, stream);
  routing_pass<0><<<kGrid, kThreads, 0, stream>>>(u, W, nullptr, s);
  squash_kernel<0><<<1, kThreads, 0, stream>>>(s, vprev, out);

  // r = 1: logits = u_hat . v0 ; v1 = squash(s1) ; vprev = v0 + v1
  routing_pass<1><<<kGrid, kThreads, 0, stream>>>(u, W, vprev, s);
  squash_kernel<1><<<1, kThreads, 0, stream>>>(s, vprev, out);

  // r = 2: logits = u_hat . (v0+v1) ; out = squash(s2)
  routing_pass<1><<<kGrid, kThreads, 0, stream>>>(u, W, vprev, s);
  squash_kernel<2><<<1, kThreads, 0, stream>>>(s, vprev, out);
}